// Round 4
// baseline (481.042 us; speedup 1.0000x reference)
//
#include <hip/hip_runtime.h>
#include <cstdint>
#include <cstddef>

typedef __bf16 bf16;
typedef bf16 bf16x4 __attribute__((ext_vector_type(4)));
typedef bf16 bf16x8 __attribute__((ext_vector_type(8)));
typedef float f32x4 __attribute__((ext_vector_type(4)));

#define NB 4
#define BATCH 512
#define BS 2048
#define NPAIRS 10
#define KQ 4            // k-split -> 4 wgs/CU (32KB LDS, ~64 VGPR)
#define KSPAN (BS / KQ) // 512

// out-block -> (count, input block j, weight index k)
__constant__ int c_npairs[NB] = {2, 3, 3, 2};
__constant__ int c_pj[NB][3]  = {{0, 1, 0}, {0, 1, 2}, {1, 2, 3}, {2, 3, 0}};
__constant__ int c_pk[NB][3]  = {{0, 1, 0}, {2, 3, 4}, {5, 6, 7}, {8, 9, 0}};

// ------------------------------------------------------- convert W+X+bias ---
__global__ __launch_bounds__(256) void cvt_kernel(
    const float* __restrict__ X, const float* __restrict__ W,
    const float* __restrict__ b,
    bf16* __restrict__ Xbf, bf16* __restrict__ Wbf, float* __restrict__ bias4)
{
    const int nW4 = NPAIRS * BS * BS / 4;   // 10,485,760 float4
    const int nX4 = NB * BATCH * BS / 4;    //  1,048,576 float4
    int idx    = blockIdx.x * 256 + threadIdx.x;   // 8192 blocks -> 2,097,152
    int stride = 8192 * 256;
    const float4* W4 = (const float4*)W;
    const float4* X4 = (const float4*)X;
    for (int i = idx; i < nW4; i += stride) {
        float4 v = W4[i];
        bf16x4 o = { (bf16)v.x, (bf16)v.y, (bf16)v.z, (bf16)v.w };
        *(bf16x4*)(Wbf + 4 * (size_t)i) = o;
    }
    if (idx < nX4) {
        float4 v = X4[idx];
        bf16x4 o = { (bf16)v.x, (bf16)v.y, (bf16)v.z, (bf16)v.w };
        *(bf16x4*)(Xbf + 4 * (size_t)idx) = o;
    }
    if (idx < NB * BS) {                    // fp32 bias sums per out-block
        int i = idx >> 11;
        int o2 = idx & (BS - 1);
        float s = 0.f;
        int np = c_npairs[i];
        for (int p = 0; p < np; ++p) s += b[c_pk[i][p] * BS + o2];
        bias4[idx] = s;
    }
}

// ------------------------------------------------------------------ gemm ---
typedef __attribute__((address_space(1))) void void_g;
typedef __attribute__((address_space(3))) void void_l;

__device__ __forceinline__ void gload16(const bf16* g, bf16* l)
{
    // async 16B global->LDS; LDS dest = wave-uniform base + lane*16
    __builtin_amdgcn_global_load_lds((void_g*)g, (void_l*)l, 16, 0, 0);
}

// P[ib*KQ+kq] = partial GEMM over k in [kq*KSPAN,(kq+1)*KSPAN) of all pairs.
// 128x128 tile, 4 waves (2x2), 4x4 16x16x32 bf16 MFMA, double-buffered LDS
// with a SINGLE barrier per K-step: prefetch of step s+1 is issued after the
// barrier, so the next barrier's vmcnt(0) drain only catches stragglers.
__global__ __launch_bounds__(256, 4) void gemm_ksplit(
    const bf16* __restrict__ Xbf,   // [NB][BATCH][BS]
    const bf16* __restrict__ Wbf,   // [NPAIRS][BS][BS] (row = out feat, K contig)
    float* __restrict__ P)          // [NB*KQ][BATCH][BS] fp32 partials
{
    __shared__ bf16 sA[2][128 * 32];   // 2 x 8 KB
    __shared__ bf16 sB[2][128 * 32];   // 2 x 8 KB

    const int tid  = threadIdx.x;
    const int lane = tid & 63;
    const int wid  = tid >> 6;
    const int wm   = (wid & 1) * 64;
    const int wn   = (wid >> 1) * 64;
    const int z    = blockIdx.z;    // ib*KQ + kq
    const int ib   = z >> 2;
    const int kq   = z & 3;
    const int bm0  = blockIdx.y * 128;
    const int bn0  = blockIdx.x * 128;
    const int np     = c_npairs[ib];
    const int nsteps = np * (KSPAN / 32);   // 32 or 48

    f32x4 acc[4][4];
    const f32x4 zero = {0.f, 0.f, 0.f, 0.f};
#pragma unroll
    for (int i = 0; i < 4; ++i)
#pragma unroll
        for (int j = 0; j < 4; ++j) acc[i][j] = zero;

    // staging: thread t -> row t>>2 (2 rounds of 64 rows), k-chunk (t&3)*8
    const int srow = tid >> 2;
    const int skp  = (tid & 3) * 8;

    // wave-uniform pair base pointers (pair selected by uniform s>>4)
    const bf16* A_0 = Xbf + ((size_t)c_pj[ib][0] * BATCH + bm0 + srow) * BS + kq * KSPAN + skp;
    const bf16* A_1 = Xbf + ((size_t)c_pj[ib][1] * BATCH + bm0 + srow) * BS + kq * KSPAN + skp;
    const bf16* A_2 = Xbf + ((size_t)c_pj[ib][2] * BATCH + bm0 + srow) * BS + kq * KSPAN + skp;
    const bf16* B_0 = Wbf + ((size_t)c_pk[ib][0] * BS + bn0 + srow) * BS + kq * KSPAN + skp;
    const bf16* B_1 = Wbf + ((size_t)c_pk[ib][1] * BS + bn0 + srow) * BS + kq * KSPAN + skp;
    const bf16* B_2 = Wbf + ((size_t)c_pk[ib][2] * BS + bn0 + srow) * BS + kq * KSPAN + skp;

    const int lm = lane & 15;
    const int lk = (lane >> 4) * 8;

    auto stage = [&](int s, int buf) {
        const int p  = s >> 4;                 // wave-uniform
        const int k0 = (s & 15) * 32;
        const bf16* Ab = (p == 0) ? A_0 : ((p == 1) ? A_1 : A_2);
        const bf16* Bb = (p == 0) ? B_0 : ((p == 1) ? B_1 : B_2);
        bf16* la = &sA[buf][tid * 8];
        bf16* lb = &sB[buf][tid * 8];
        gload16(Ab + k0,           la);
        gload16(Ab + 64 * BS + k0, la + 2048);
        gload16(Bb + k0,           lb);
        gload16(Bb + 64 * BS + k0, lb + 2048);
    };

    stage(0, 0);   // prologue fill of buffer 0

    for (int s = 0; s < nsteps; ++s) {
        const int cur = s & 1;
        __syncthreads();                 // drains stage(s) vmcnt; fences prev reads
        if (s + 1 < nsteps) stage(s + 1, cur ^ 1);   // lands during this compute

        bf16x8 af[4], bfr[4];
#pragma unroll
        for (int mi = 0; mi < 4; ++mi)
            af[mi] = *(const bf16x8*)(&sA[cur][(wm + mi * 16 + lm) * 32 + lk]);
#pragma unroll
        for (int ni = 0; ni < 4; ++ni)
            bfr[ni] = *(const bf16x8*)(&sB[cur][(wn + ni * 16 + lm) * 32 + lk]);
#pragma unroll
        for (int mi = 0; mi < 4; ++mi)
#pragma unroll
            for (int ni = 0; ni < 4; ++ni)
                acc[mi][ni] = __builtin_amdgcn_mfma_f32_16x16x32_bf16(
                    af[mi], bfr[ni], acc[mi][ni], 0, 0, 0);
    }

    // epilogue: raw fp32 partials (C/D: col=lane&15, row=(lane>>4)*4+reg)
    float* Pt = P + ((size_t)z * BATCH + bm0) * BS + bn0;
#pragma unroll
    for (int mi = 0; mi < 4; ++mi) {
#pragma unroll
        for (int ni = 0; ni < 4; ++ni) {
            const int m = wm + mi * 16 + (lane >> 4) * 4;
            const int n = wn + ni * 16 + lm;
#pragma unroll
            for (int r = 0; r < 4; ++r)
                Pt[(size_t)(m + r) * BS + n] = acc[mi][ni][r];
        }
    }
}

// --------------------------------------------------------------- combine ---
__global__ __launch_bounds__(256) void combine_kernel(
    const float* __restrict__ P, const float* __restrict__ bias4,
    bf16* __restrict__ Xnext, float* __restrict__ Yout, int write_f32)
{
    const int e4 = blockIdx.x * 256 + threadIdx.x;  // 4096 blocks -> 1,048,576
    const int ib  = e4 >> 18;                       // 262144 float4 per z-slice
    const int loc = e4 & 262143;
    const float4* Pb = (const float4*)P + (size_t)(ib * KQ) * 262144 + loc;
    float4 p0 = Pb[0];
    float4 p1 = Pb[262144];
    float4 p2 = Pb[2 * 262144];
    float4 p3 = Pb[3 * 262144];
    const int n4 = e4 & 511;
    float4 bv = ((const float4*)bias4)[ib * 512 + n4];
    float sx = p0.x + p1.x + p2.x + p3.x + bv.x;
    float sy = p0.y + p1.y + p2.y + p3.y + bv.y;
    float sz = p0.z + p1.z + p2.z + p3.z + bv.z;
    float sw = p0.w + p1.w + p2.w + p3.w + bv.w;
    sx = sx > 0.f ? sx : 0.f;
    sy = sy > 0.f ? sy : 0.f;
    sz = sz > 0.f ? sz : 0.f;
    sw = sw > 0.f ? sw : 0.f;
    if (write_f32) {
        float4 o = { sx, sy, sz, sw };
        ((float4*)Yout)[e4] = o;
    } else {
        bf16x4 o = { (bf16)sx, (bf16)sy, (bf16)sz, (bf16)sw };
        *(bf16x4*)(Xnext + 4 * (size_t)e4) = o;
    }
}

// ----------------------------------------------------------------- launch ---
extern "C" void kernel_launch(void* const* d_in, const int* in_sizes, int n_in,
                              void* d_out, int out_size, void* d_ws, size_t ws_size,
                              hipStream_t stream)
{
    const float* X = (const float*)d_in[0];
    const float* W = (const float*)d_in[1];
    const float* b = (const float*)d_in[2];
    float* out = (float*)d_out;
    char* ws = (char*)d_ws;

    const size_t W_BYTES   = (size_t)NPAIRS * BS * BS * 2;       // 83,886,080
    const size_t XBF_BYTES = (size_t)NB * BATCH * BS * 2;        //  8,388,608
    const size_t P_BYTES   = (size_t)NB * KQ * BATCH * BS * 4;   // 67,108,864

    bf16*  Wbf   = (bf16*)ws;
    bf16*  Xbf0  = (bf16*)(ws + W_BYTES);
    bf16*  Xbf1  = (bf16*)(ws + W_BYTES + XBF_BYTES);
    float* P     = (float*)(ws + W_BYTES + 2 * XBF_BYTES);
    float* bias4 = (float*)(ws + W_BYTES + 2 * XBF_BYTES + P_BYTES); // ~168 MB

    hipLaunchKernelGGL(cvt_kernel, dim3(8192), dim3(256), 0, stream,
                       X, W, b, Xbf0, Wbf, bias4);

    dim3 grid(BS / 128, BATCH / 128, NB * KQ);   // (16, 4, 16) = 1024 wgs
    hipLaunchKernelGGL(gemm_ksplit, grid, dim3(256), 0, stream, Xbf0, Wbf, P);
    hipLaunchKernelGGL(combine_kernel, dim3(4096), dim3(256), 0, stream,
                       P, bias4, Xbf1, (float*)nullptr, 0);
    hipLaunchKernelGGL(gemm_ksplit, grid, dim3(256), 0, stream, Xbf1, Wbf, P);
    hipLaunchKernelGGL(combine_kernel, dim3(4096), dim3(256), 0, stream,
                       P, bias4, (bf16*)nullptr, out, 1);
}

// Round 6
// 378.244 us; speedup vs baseline: 1.2718x; 1.2718x over previous
//
#include <hip/hip_runtime.h>
#include <cstdint>
#include <cstddef>

typedef __bf16 bf16;
typedef bf16 bf16x4 __attribute__((ext_vector_type(4)));
typedef bf16 bf16x8 __attribute__((ext_vector_type(8)));
typedef float f32x4 __attribute__((ext_vector_type(4)));

#define NB 4
#define BATCH 512
#define BS 2048
#define NPAIRS 10
#define KQ 4            // k-split -> 4 wgs/CU (32KB LDS, ~64 VGPR)
#define KSPAN (BS / KQ) // 512

// out-block -> (count, input block j, weight index k)
__constant__ int c_npairs[NB] = {2, 3, 3, 2};
__constant__ int c_pj[NB][3]  = {{0, 1, 0}, {0, 1, 2}, {1, 2, 3}, {2, 3, 0}};
__constant__ int c_pk[NB][3]  = {{0, 1, 0}, {2, 3, 4}, {5, 6, 7}, {8, 9, 0}};

// ------------------------------------------------------- convert W+X+bias ---
__global__ __launch_bounds__(256) void cvt_kernel(
    const float* __restrict__ X, const float* __restrict__ W,
    const float* __restrict__ b,
    bf16* __restrict__ Xbf, bf16* __restrict__ Wbf, float* __restrict__ bias4)
{
    const int nW4 = NPAIRS * BS * BS / 4;   // 10,485,760 float4
    const int nX4 = NB * BATCH * BS / 4;    //  1,048,576 float4
    int idx    = blockIdx.x * 256 + threadIdx.x;   // 8192 blocks -> 2,097,152
    int stride = 8192 * 256;
    const float4* W4 = (const float4*)W;
    const float4* X4 = (const float4*)X;
    for (int i = idx; i < nW4; i += stride) {
        float4 v = W4[i];
        bf16x4 o = { (bf16)v.x, (bf16)v.y, (bf16)v.z, (bf16)v.w };
        *(bf16x4*)(Wbf + 4 * (size_t)i) = o;
    }
    if (idx < nX4) {
        float4 v = X4[idx];
        bf16x4 o = { (bf16)v.x, (bf16)v.y, (bf16)v.z, (bf16)v.w };
        *(bf16x4*)(Xbf + 4 * (size_t)idx) = o;
    }
    if (idx < NB * BS) {                    // fp32 bias sums per out-block
        int i = idx >> 11;
        int o2 = idx & (BS - 1);
        float s = 0.f;
        int np = c_npairs[i];
        for (int p = 0; p < np; ++p) s += b[c_pk[i][p] * BS + o2];
        bias4[idx] = s;
    }
}

// ------------------------------------------------------------------ gemm ---
typedef __attribute__((address_space(1))) void void_g;
typedef __attribute__((address_space(3))) void void_l;

__device__ __forceinline__ void gload16(const bf16* g, bf16* l)
{
    // async 16B global->LDS; LDS dest = wave-uniform base + lane*16
    __builtin_amdgcn_global_load_lds((void_g*)g, (void_l*)l, 16, 0, 0);
}

// P[ib*KQ+kq] = partial GEMM over k in [kq*KSPAN,(kq+1)*KSPAN) of all pairs.
// R3-verified 2-barrier structure, widened to BK=64: each barrier pair stages
// TWO K32 panels (8 x global_load_lds) then runs both MFMA panels — half the
// barrier-drain events of R3 at identical LDS/VGPR budget (4 wgs/CU).
__global__ __launch_bounds__(256, 4) void gemm_ksplit(
    const bf16* __restrict__ Xbf,   // [NB][BATCH][BS]
    const bf16* __restrict__ Wbf,   // [NPAIRS][BS][BS] (row = out feat, K contig)
    float* __restrict__ P)          // [NB*KQ][BATCH][BS] fp32 partials
{
    __shared__ bf16 sA[2 * 128 * 32];   // 2 K32 panels, 16 KB
    __shared__ bf16 sB[2 * 128 * 32];   // 16 KB

    const int tid  = threadIdx.x;
    const int lane = tid & 63;
    const int wid  = tid >> 6;
    const int wm   = (wid & 1) * 64;
    const int wn   = (wid >> 1) * 64;
    const int z    = blockIdx.z;    // ib*KQ + kq
    const int ib   = z >> 2;
    const int kq   = z & 3;
    const int bm0  = blockIdx.y * 128;
    const int bn0  = blockIdx.x * 128;

    f32x4 acc[4][4];
    const f32x4 zero = {0.f, 0.f, 0.f, 0.f};
#pragma unroll
    for (int i = 0; i < 4; ++i)
#pragma unroll
        for (int j = 0; j < 4; ++j) acc[i][j] = zero;

    // staging: thread t -> row t>>2 (2 rounds of 64 rows), k-chunk (t&3)*8
    const int srow = tid >> 2;
    const int skp  = (tid & 3) * 8;
    bf16* ldsA0 = sA + (size_t)tid * 8;          // panel0 rows 0..63
    bf16* ldsA1 = sA + 2048 + (size_t)tid * 8;   // panel0 rows 64..127
    bf16* ldsB0 = sB + (size_t)tid * 8;
    bf16* ldsB1 = sB + 2048 + (size_t)tid * 8;

    // fragment coords (verified gfx950 16x16x32 layout)
    const int lm = lane & 15;
    const int lk = (lane >> 4) * 8;

    const int np = c_npairs[ib];
    for (int p = 0; p < np; ++p) {
        const bf16* Ab = Xbf + ((size_t)c_pj[ib][p] * BATCH + bm0 + srow) * BS
                             + kq * KSPAN + skp;
        const bf16* Bb = Wbf + ((size_t)c_pk[ib][p] * BS    + bn0 + srow) * BS
                             + kq * KSPAN + skp;
        for (int k0 = 0; k0 < KSPAN; k0 += 64) {
            __syncthreads();                      // prev step's ds_reads done
            gload16(Ab + k0,                ldsA0);          // panel0
            gload16(Ab + 64 * BS + k0,      ldsA1);
            gload16(Bb + k0,                ldsB0);
            gload16(Bb + 64 * BS + k0,      ldsB1);
            gload16(Ab + k0 + 32,           ldsA0 + 4096);   // panel1
            gload16(Ab + 64 * BS + k0 + 32, ldsA1 + 4096);
            gload16(Bb + k0 + 32,           ldsB0 + 4096);
            gload16(Bb + 64 * BS + k0 + 32, ldsB1 + 4096);
            __syncthreads();                      // vmcnt drain -> LDS valid
#pragma unroll
            for (int q = 0; q < 2; ++q) {
                bf16x8 af[4], bfr[4];
#pragma unroll
                for (int mi = 0; mi < 4; ++mi)
                    af[mi] = *(const bf16x8*)(sA + q * 4096
                                              + (wm + mi * 16 + lm) * 32 + lk);
#pragma unroll
                for (int ni = 0; ni < 4; ++ni)
                    bfr[ni] = *(const bf16x8*)(sB + q * 4096
                                               + (wn + ni * 16 + lm) * 32 + lk);
#pragma unroll
                for (int mi = 0; mi < 4; ++mi)
#pragma unroll
                    for (int ni = 0; ni < 4; ++ni)
                        acc[mi][ni] = __builtin_amdgcn_mfma_f32_16x16x32_bf16(
                            af[mi], bfr[ni], acc[mi][ni], 0, 0, 0);
            }
        }
    }

    // epilogue: raw fp32 partials (C/D: col=lane&15, row=(lane>>4)*4+reg)
    float* Pt = P + ((size_t)z * BATCH + bm0) * BS + bn0;
#pragma unroll
    for (int mi = 0; mi < 4; ++mi) {
#pragma unroll
        for (int ni = 0; ni < 4; ++ni) {
            const int m = wm + mi * 16 + (lane >> 4) * 4;
            const int n = wn + ni * 16 + lm;
#pragma unroll
            for (int r = 0; r < 4; ++r)
                Pt[(size_t)(m + r) * BS + n] = acc[mi][ni][r];
        }
    }
}

// --------------------------------------------------------------- combine ---
__global__ __launch_bounds__(256) void combine_kernel(
    const float* __restrict__ P, const float* __restrict__ bias4,
    bf16* __restrict__ Xnext, float* __restrict__ Yout, int write_f32)
{
    const int e4 = blockIdx.x * 256 + threadIdx.x;  // 4096 blocks -> 1,048,576
    const int ib  = e4 >> 18;                       // 262144 float4 per z-slice
    const int loc = e4 & 262143;
    const float4* Pb = (const float4*)P + (size_t)(ib * KQ) * 262144 + loc;
    float4 p0 = Pb[0];
    float4 p1 = Pb[262144];
    float4 p2 = Pb[2 * 262144];
    float4 p3 = Pb[3 * 262144];
    const int n4 = e4 & 511;
    float4 bv = ((const float4*)bias4)[ib * 512 + n4];
    float sx = p0.x + p1.x + p2.x + p3.x + bv.x;
    float sy = p0.y + p1.y + p2.y + p3.y + bv.y;
    float sz = p0.z + p1.z + p2.z + p3.z + bv.z;
    float sw = p0.w + p1.w + p2.w + p3.w + bv.w;
    sx = sx > 0.f ? sx : 0.f;
    sy = sy > 0.f ? sy : 0.f;
    sz = sz > 0.f ? sz : 0.f;
    sw = sw > 0.f ? sw : 0.f;
    if (write_f32) {
        float4 o = { sx, sy, sz, sw };
        ((float4*)Yout)[e4] = o;
    } else {
        bf16x4 o = { (bf16)sx, (bf16)sy, (bf16)sz, (bf16)sw };
        *(bf16x4*)(Xnext + 4 * (size_t)e4) = o;
    }
}

// ----------------------------------------------------------------- launch ---
extern "C" void kernel_launch(void* const* d_in, const int* in_sizes, int n_in,
                              void* d_out, int out_size, void* d_ws, size_t ws_size,
                              hipStream_t stream)
{
    const float* X = (const float*)d_in[0];
    const float* W = (const float*)d_in[1];
    const float* b = (const float*)d_in[2];
    float* out = (float*)d_out;
    char* ws = (char*)d_ws;

    const size_t W_BYTES   = (size_t)NPAIRS * BS * BS * 2;       // 83,886,080
    const size_t XBF_BYTES = (size_t)NB * BATCH * BS * 2;        //  8,388,608
    const size_t P_BYTES   = (size_t)NB * KQ * BATCH * BS * 4;   // 67,108,864

    bf16*  Wbf   = (bf16*)ws;
    bf16*  Xbf0  = (bf16*)(ws + W_BYTES);
    bf16*  Xbf1  = (bf16*)(ws + W_BYTES + XBF_BYTES);
    float* P     = (float*)(ws + W_BYTES + 2 * XBF_BYTES);
    float* bias4 = (float*)(ws + W_BYTES + 2 * XBF_BYTES + P_BYTES); // ~168 MB

    hipLaunchKernelGGL(cvt_kernel, dim3(8192), dim3(256), 0, stream,
                       X, W, b, Xbf0, Wbf, bias4);

    dim3 grid(BS / 128, BATCH / 128, NB * KQ);   // (16, 4, 16) = 1024 wgs
    hipLaunchKernelGGL(gemm_ksplit, grid, dim3(256), 0, stream, Xbf0, Wbf, P);
    hipLaunchKernelGGL(combine_kernel, dim3(4096), dim3(256), 0, stream,
                       P, bias4, Xbf1, (float*)nullptr, 0);
    hipLaunchKernelGGL(gemm_ksplit, grid, dim3(256), 0, stream, Xbf1, Wbf, P);
    hipLaunchKernelGGL(combine_kernel, dim3(4096), dim3(256), 0, stream,
                       P, bias4, (bf16*)nullptr, out, 1);
}